// Round 6
// baseline (612.227 us; speedup 1.0000x reference)
//
#include <hip/hip_runtime.h>

#define B_TOT 4096
#define S_LEN 1024
#define HID   30
#define SKIP  16
#define HLEN  (S_LEN - SKIP)   // 1008
#define WSTR  20               // LDS words per batch row (16B-align + bank spread)

typedef __attribute__((ext_vector_type(8))) short bf16x8;
typedef __attribute__((ext_vector_type(4))) float f32x4;
typedef __attribute__((ext_vector_type(4))) int   i32x4;

__device__ __forceinline__ unsigned fb(float x){ return __float_as_uint(x); }
// pack two floats as bf16 (truncation): low16 = a, high16 = b
__device__ __forceinline__ unsigned pkbf(float a, float b){
  return (fb(a) >> 16) | (fb(b) & 0xFFFF0000u);
}
__device__ __forceinline__ float hif(float a){
  return __uint_as_float(fb(a) & 0xFFFF0000u);
}
__device__ __forceinline__ float sigmoid_fast(float z){
  float e = __builtin_amdgcn_exp2f(z * -1.442695041f);
  return __builtin_amdgcn_rcpf(1.0f + e);
}
__device__ __forceinline__ f32x4 mfma_bf16(i32x4 a, i32x4 b, f32x4 c){
  return __builtin_amdgcn_mfma_f32_16x16x32_bf16(
      __builtin_bit_cast(bf16x8, a), __builtin_bit_cast(bf16x8, b), c, 0, 0, 0);
}
// sum over lanes {n, n+16, n+32, n+48} (same n=lane&15); valid in all lanes
__device__ __forceinline__ float red4(float v, int bp32){
  v += __int_as_float(__builtin_amdgcn_ds_swizzle(__float_as_int(v), 0x401F));
  v += __int_as_float(__builtin_amdgcn_ds_bpermute(bp32, __float_as_int(v)));
  return v;
}
// extended 32x32 weight matrix: rows 0..29 = Wh (cols30,31 = wx0,wx1),
// row30 = W2 (x-cols 0), row31 = 0
__device__ __forceinline__ float wext(const float* Wh, const float* Wx,
                                      const float* W2, int r, int c){
  if (r >= 31) return 0.f;
  if (r == 30) return (c < HID) ? W2[c] : 0.f;
  if (c < HID) return Wh[r*HID + c];
  return (c == 30) ? Wx[r*7 + 0] : Wx[r*7 + 1];
}

__global__ __launch_bounds__(64) void mminet_mfma(
    const float* __restrict__ x,   const float* __restrict__ var,
    const float* __restrict__ amps,const float* __restrict__ s0,
    const float* __restrict__ W1,  const float* __restrict__ b1,
    const float* __restrict__ Wx,  const float* __restrict__ Wh,
    const float* __restrict__ W2,  const float* __restrict__ b2,
    const float* __restrict__ Wm1, const float* __restrict__ bm1,
    const float* __restrict__ Wm2, const float* __restrict__ bm2,
    const float* __restrict__ Wm3, const float* __restrict__ bm3,
    float* __restrict__ Hout, float* __restrict__ out2)
{
  __shared__ __align__(16) unsigned hbuf[2][16 * WSTR];  // [hi|lo] bf16 pair-words
  __shared__ float h1s[16][64];                          // MLP epilogue

  const int lane = threadIdx.x;        // 0..63, one wave per block
  const int n    = lane & 15;          // batch within tile / MFMA col
  const int q    = lane >> 4;          // quad
  const int b    = blockIdx.x * 16 + n;
  const int bp32 = ((lane ^ 32) << 2);

  const float v0 = var[b*4+0], v1 = var[b*4+1], v2 = var[b*4+2], v3 = var[b*4+3];
  const float am0 = amps[b*2+0], am1 = amps[b*2+1];

  // ---- A fragments (4 tiles: hi/lo x top/bottom), built once ----
  i32x4 AhiT, AloT, AhiB, AloB;
#pragma unroll
  for (int w = 0; w < 4; ++w) {
    float c0 = wext(Wh, Wx, W2, n, 8*q + 2*w);
    float c1 = wext(Wh, Wx, W2, n, 8*q + 2*w + 1);
    AhiT[w] = pkbf(c0, c1);
    AloT[w] = pkbf(c0 - hif(c0), c1 - hif(c1));
    float d0 = wext(Wh, Wx, W2, 16 + n, 8*q + 2*w);
    float d1 = wext(Wh, Wx, W2, 16 + n, 8*q + 2*w + 1);
    AhiB[w] = pkbf(d0, d1);
    AloB[w] = pkbf(d0 - hif(d0), d1 - hif(d1));
  }

  // ---- per-lane constants for the 8 owned C-rows (4q+i, 16+4q+i) ----
  float cv[8], wx2a[8], w1a[8], w2a[8], ra[8], rs[8], s1v[8];
#pragma unroll
  for (int i = 0; i < 8; ++i) {
    int rr = (i < 4) ? (4*q + i) : (12 + 4*q + i);   // 16+4q+(i-4)
    bool on = rr < HID;
    cv[i]   = on ? (Wx[rr*7+3]*v0 + Wx[rr*7+4]*v1 + Wx[rr*7+5]*v2 + Wx[rr*7+6]*v3) : 0.f;
    wx2a[i] = on ? Wx[rr*7+2] : 0.f;
    w1a[i]  = on ? W1[rr] : 0.f;
    w2a[i]  = on ? W2[rr] : 0.f;
    ra[i]   = on ? ((float)(rr+1) * (5.0f/30.0f)) : 1.f;
    float rsum = 0.f;
    if (on) for (int c = 0; c < HID; ++c) rsum += Wh[rr*HID + c];
    rs[i]   = rsum;
    s1v[i]  = on ? s0[b*HID + rr] : 0.f;
  }

  const float hcst = W1[30]*v0 + W1[31]*v1 + W1[32]*v2 + W1[33]*v3 + b1[0];
  const float hc2  = hcst + b2[0];
  float sw2 = 0.f;
#pragma unroll
  for (int i = 0; i < 8; ++i) sw2 += w2a[i];
  const float sumW2 = red4(sw2, bp32);

  const float4* xb4 = (const float4*)(x + (size_t)b * S_LEN * 4);
  unsigned* hbn = &hbuf[0][n * WSTR];
  unsigned* lbn = &hbuf[1][n * WSTR];

  // ---- prologue: s1_0, part, hpre; seed B with hpre + x_0 slots ----
  float4 xq = xb4[0], xn = xb4[1], xn2 = xb4[2];
  float xpx = 0.f;
#pragma unroll
  for (int i = 0; i < 8; ++i)
    s1v[i] = __builtin_amdgcn_fmed3f(s1v[i] + xq.y, -ra[i], ra[i]);
  float part = 0.f;
#pragma unroll
  for (int i = 0; i < 8; ++i) part = fmaf(w1a[i], s1v[i], part);
  const float Hh0  = red4(part, bp32) + hcst;
  const float hpre = (xq.x - Hh0) / sumW2;
  {
    unsigned hpw = pkbf(hpre, hpre);
    float    hpl = hpre - hif(hpre);
    unsigned lpw = pkbf(hpl, hpl);
    uint2 wt; wt.x = hpw; wt.y = hpw;
    uint2 wb; wb.x = hpw; wb.y = (q == 3) ? pkbf(xq.x, xq.z) : hpw;
    *(uint2*)&hbn[2*q]     = wt;
    *(uint2*)&hbn[8 + 2*q] = wb;
    uint2 lt; lt.x = lpw; lt.y = lpw;
    uint2 lb; lb.x = lpw;
    lb.y = (q == 3) ? pkbf(xq.x - hif(xq.x), xq.z - hif(xq.z)) : lpw;
    *(uint2*)&lbn[2*q]     = lt;
    *(uint2*)&lbn[8 + 2*q] = lb;
  }
  i32x4 Bhi = *(i32x4*)&hbn[4*q];
  i32x4 Blo = *(i32x4*)&lbn[4*q];

  // ---- main scan ----
  float P = 0.f, Hm1 = 0.f, Bm1 = 0.f;
  float4 hacc = make_float4(0.f, 0.f, 0.f, 0.f);
  f32x4 h4T, h4B;

  for (int t = 0; t < S_LEN; ++t) {
    if (t > 0) {                                   // s1_t (prologue did t=0)
#pragma unroll
      for (int i = 0; i < 8; ++i)
        s1v[i] = __builtin_amdgcn_fmed3f(s1v[i] + xq.y, -ra[i], ra[i]);
    }

    // z_t = Wext * [h_{t-1} | x0_t, x2_t]  (+ cvar + wx2*x3_t via C-init)
    f32x4 CT, CB;
#pragma unroll
    for (int i = 0; i < 4; ++i) {
      CT[i] = fmaf(wx2a[i],     xq.w, cv[i]);
      CB[i] = fmaf(wx2a[4 + i], xq.w, cv[4 + i]);
    }
    f32x4 zT = mfma_bf16(AhiT, Bhi, CT);
    zT = mfma_bf16(AloT, Bhi, zT);
    zT = mfma_bf16(AhiT, Blo, zT);
    f32x4 zB = mfma_bf16(AhiB, Bhi, CB);
    zB = mfma_bf16(AloB, Bhi, zB);
    zB = mfma_bf16(AhiB, Blo, zB);

    // emit H_{t-1} (uses part = w1.s1_{t-1}; zB[2] row30 = w2.h_{t-1})
    if (t >= SKIP + 1) {
      float H = red4(part, bp32) + zB[2] + hc2;    // valid on q==3
      int idx = t - (SKIP + 1);
      if (idx > 0) P = fmaf(xpx - Bm1, H + Hm1, P);
      Hm1 = H; Bm1 = xpx;
      hacc.x = hacc.y; hacc.y = hacc.z; hacc.z = hacc.w; hacc.w = H;
      if ((idx & 3) == 3 && q == 3)
        *(float4*)(Hout + (size_t)b * HLEN + (idx - 3)) = hacc;
    }

    // part for step t
    part = 0.f;
#pragma unroll
    for (int i = 0; i < 8; ++i) part = fmaf(w1a[i], s1v[i], part);

    // h_t = sigmoid(z_t)
#pragma unroll
    for (int i = 0; i < 4; ++i) { h4T[i] = sigmoid_fast(zT[i]); h4B[i] = sigmoid_fast(zB[i]); }

    // write h_t (hi/lo bf16) + x_{t+1} slots; read next B fragments
    {
      unsigned t0 = pkbf(h4T[0], h4T[1]), t1 = pkbf(h4T[2], h4T[3]);
      unsigned b0 = pkbf(h4B[0], h4B[1]);
      unsigned b1w = (q == 3) ? pkbf(xn.x, xn.z) : pkbf(h4B[2], h4B[3]);
      float l0 = h4T[0] - hif(h4T[0]), l1 = h4T[1] - hif(h4T[1]);
      float l2 = h4T[2] - hif(h4T[2]), l3 = h4T[3] - hif(h4T[3]);
      float m0 = h4B[0] - hif(h4B[0]), m1 = h4B[1] - hif(h4B[1]);
      float m2 = h4B[2] - hif(h4B[2]), m3 = h4B[3] - hif(h4B[3]);
      unsigned lt0 = pkbf(l0, l1), lt1 = pkbf(l2, l3);
      unsigned lb0 = pkbf(m0, m1);
      unsigned lb1 = (q == 3) ? pkbf(xn.x - hif(xn.x), xn.z - hif(xn.z))
                              : pkbf(m2, m3);
      uint2 a; a.x = t0; a.y = t1;   *(uint2*)&hbn[2*q]     = a;
      uint2 c; c.x = b0; c.y = b1w;  *(uint2*)&hbn[8 + 2*q] = c;
      uint2 d; d.x = lt0; d.y = lt1; *(uint2*)&lbn[2*q]     = d;
      uint2 e; e.x = lb0; e.y = lb1; *(uint2*)&lbn[8 + 2*q] = e;
      Bhi = *(i32x4*)&hbn[4*q];
      Blo = *(i32x4*)&lbn[4*q];
    }

    // rotate x; prefetch depth 3
    xpx = xq.x; xq = xn; xn = xn2;
    int tp = t + 3; if (tp > S_LEN - 1) tp = S_LEN - 1;
    xn2 = xb4[tp];
  }

  // ---- tail: H_{1023} (w2.h via VALU dot) + last P term + last store ----
  {
    float w2p = part;
#pragma unroll
    for (int i = 0; i < 4; ++i) {
      w2p = fmaf(w2a[i], h4T[i], w2p);
      w2p = fmaf(w2a[4 + i], h4B[i], w2p);
    }
    float Hl = red4(w2p, bp32) + hc2;
    P = fmaf(xpx - Bm1, Hl + Hm1, P);
    hacc.x = hacc.y; hacc.y = hacc.z; hacc.z = hacc.w; hacc.w = Hl;
    if (q == 3)
      *(float4*)(Hout + (size_t)b * HLEN + (HLEN - 4)) = hacc;
  }

  // ---- fused MLP epilogue ----
  float Pp = P * 0.5f * am0 * am1;
  Pp *= __builtin_amdgcn_exp2f(v0 * 3.321928095f);     // * 10^var0
  Pp = fmaxf(Pp, 1e-12f);
  float Pcv = __builtin_amdgcn_logf(Pp) * 0.30102999566f;  // log10
  // broadcast the valid (q==3) Pcv to all 4 q-lanes of each batch
  Pcv = __int_as_float(__builtin_amdgcn_ds_bpermute((48 + n) << 2,
                                                    __float_as_int(Pcv)));
#pragma unroll
  for (int i = 0; i < 16; ++i) {
    int e = 16*q + i;
    const float* wr = Wm1 + e * 5;
    float h1 = bm1[e] + wr[0]*v0 + wr[1]*v1 + wr[2]*v2 + wr[3]*v3 + wr[4]*Pcv;
    h1s[n][e] = fmaxf(h1, 0.f);
  }
  float sacc = 0.f;
#pragma unroll
  for (int i2 = 0; i2 < 8; ++i2) {
    int m = 8*q + i2;
    float z = bm2[m];
    const f32x4* wrow = (const f32x4*)(Wm2 + m * 64);
    const f32x4* hrow = (const f32x4*)&h1s[n][0];
#pragma unroll
    for (int e4 = 0; e4 < 16; ++e4) {
      f32x4 ww = wrow[e4], hh = hrow[e4];
      z += ww[0]*hh[0] + ww[1]*hh[1] + ww[2]*hh[2] + ww[3]*hh[3];
    }
    sacc = fmaf(Wm3[m], fmaxf(z, 0.f), sacc);
  }
  sacc = red4(sacc, bp32);
  if (q == 3) out2[b] = Pcv + sacc + bm3[0];
}

extern "C" void kernel_launch(void* const* d_in, const int* in_sizes, int n_in,
                              void* d_out, int out_size, void* d_ws, size_t ws_size,
                              hipStream_t stream)
{
  const float* x    = (const float*)d_in[0];
  const float* var  = (const float*)d_in[1];
  const float* amps = (const float*)d_in[2];
  const float* s0   = (const float*)d_in[3];
  const float* W1   = (const float*)d_in[4];
  const float* b1   = (const float*)d_in[5];
  const float* Wx   = (const float*)d_in[6];
  const float* Wh   = (const float*)d_in[7];
  const float* W2   = (const float*)d_in[8];
  const float* b2   = (const float*)d_in[9];
  const float* Wm1  = (const float*)d_in[10];
  const float* bm1  = (const float*)d_in[11];
  const float* Wm2  = (const float*)d_in[12];
  const float* bm2  = (const float*)d_in[13];
  const float* Wm3  = (const float*)d_in[14];
  const float* bm3  = (const float*)d_in[15];
  // d_in[16] = n_init (compile-time 16)

  float* Hout = (float*)d_out;
  float* out2 = (float*)d_out + (size_t)B_TOT * HLEN;

  mminet_mfma<<<B_TOT / 16, 64, 0, stream>>>(
      x, var, amps, s0, W1, b1, Wx, Wh, W2, b2,
      Wm1, bm1, Wm2, bm2, Wm3, bm3, Hout, out2);
}